// Round 1
// baseline (583.160 us; speedup 1.0000x reference)
//
#include <hip/hip_runtime.h>
#include <math.h>

#define D_MODEL 1024
#define SEQ     2048
#define BATCH   8
#define VOCAB   32000
#define PAD_ID  2

typedef float f32x4 __attribute__((ext_vector_type(4)));

// log2(10000) / 1024
#define INV_EXP_C (13.287712379549449f / 1024.0f)

// --------------------------------------------------------------------------
// PE table: pe[s*D_MODEL + d]
//   d even: cos((s+1) * 10000^(-d/1024))
//   d odd : sin((s+1) * 10000^(-(d+1)/1024))
// One block per s, 256 threads, 4 consecutive d per thread.
// --------------------------------------------------------------------------
__global__ __launch_bounds__(256) void pe_kernel(float* __restrict__ pe) {
    const int s  = blockIdx.x;
    const int d0 = threadIdx.x * 4;
    const float pos = (float)(s + 1);

    const float inv0 = exp2f(-(float)(d0)     * INV_EXP_C);
    const float inv1 = exp2f(-(float)(d0 + 2) * INV_EXP_C);
    const float inv2 = exp2f(-(float)(d0 + 4) * INV_EXP_C);

    const float a0 = pos * inv0;
    const float a1 = pos * inv1;
    const float a2 = pos * inv2;

    float s1, c1;
    sincosf(a1, &s1, &c1);

    f32x4 v;
    v.x = cosf(a0);   // i = d0     (even, exp d0/1024)
    v.y = s1;         // i = d0+1   (odd,  exp (d0+2)/1024)
    v.z = c1;         // i = d0+2   (even, exp (d0+2)/1024)
    v.w = sinf(a2);   // i = d0+3   (odd,  exp (d0+4)/1024)

    *(f32x4*)(pe + (size_t)s * D_MODEL + d0) = v;
}

// --------------------------------------------------------------------------
// Fused embedding-gather + PE-add + pad-mask broadcast.
// grid = (SEQ, BATCH), 256 threads.
// Block (s, b):
//   emb[b][s][d]  = weight[d][tok] + bias[d] + pe[s][d]   (4 d per thread)
//   mask[b][s][j] = (x[b][j] == PAD_ID) ? 1 : 0           (8 j per thread)
// --------------------------------------------------------------------------
template <bool USE_TABLE>
__global__ __launch_bounds__(256) void emb_mask_kernel(
        const int*   __restrict__ x,
        const float* __restrict__ w,
        const float* __restrict__ bias,
        const float* __restrict__ pe,
        float*       __restrict__ emb,
        float*       __restrict__ mask) {
    const int s = blockIdx.x;
    const int b = blockIdx.y;
    const int t = threadIdx.x;

    const int tok = x[b * SEQ + s];   // uniform per block; L1-broadcast

    // ---- embedding part: 4 consecutive d per thread ----
    const int d0 = t * 4;
    const float* wc = w + tok;
    const float w0 = wc[(size_t)(d0 + 0) * VOCAB];
    const float w1 = wc[(size_t)(d0 + 1) * VOCAB];
    const float w2 = wc[(size_t)(d0 + 2) * VOCAB];
    const float w3 = wc[(size_t)(d0 + 3) * VOCAB];

    const f32x4 bv = *(const f32x4*)(bias + d0);

    f32x4 pv;
    if (USE_TABLE) {
        pv = *(const f32x4*)(pe + (size_t)s * D_MODEL + d0);
    } else {
        const float pos  = (float)(s + 1);
        const float inv0 = exp2f(-(float)(d0)     * INV_EXP_C);
        const float inv1 = exp2f(-(float)(d0 + 2) * INV_EXP_C);
        const float inv2 = exp2f(-(float)(d0 + 4) * INV_EXP_C);
        float s1, c1;
        sincosf(pos * inv1, &s1, &c1);
        pv.x = cosf(pos * inv0);
        pv.y = s1;
        pv.z = c1;
        pv.w = sinf(pos * inv2);
    }

    f32x4 o;
    o.x = (w0 + bv.x) + pv.x;
    o.y = (w1 + bv.y) + pv.y;
    o.z = (w2 + bv.z) + pv.z;
    o.w = (w3 + bv.w) + pv.w;

    f32x4* eptr = (f32x4*)(emb + ((size_t)(b * SEQ + s)) * D_MODEL + d0);
    __builtin_nontemporal_store(o, eptr);

    // ---- mask part: 8 consecutive j per thread ----
    const int j0 = t * 8;
    const int4 xi0 = *(const int4*)(x + b * SEQ + j0);
    const int4 xi1 = *(const int4*)(x + b * SEQ + j0 + 4);

    f32x4 m0, m1;
    m0.x = (xi0.x == PAD_ID) ? 1.0f : 0.0f;
    m0.y = (xi0.y == PAD_ID) ? 1.0f : 0.0f;
    m0.z = (xi0.z == PAD_ID) ? 1.0f : 0.0f;
    m0.w = (xi0.w == PAD_ID) ? 1.0f : 0.0f;
    m1.x = (xi1.x == PAD_ID) ? 1.0f : 0.0f;
    m1.y = (xi1.y == PAD_ID) ? 1.0f : 0.0f;
    m1.z = (xi1.z == PAD_ID) ? 1.0f : 0.0f;
    m1.w = (xi1.w == PAD_ID) ? 1.0f : 0.0f;

    float* mrow = mask + ((size_t)b * SEQ + s) * SEQ + j0;
    __builtin_nontemporal_store(m0, (f32x4*)mrow);
    __builtin_nontemporal_store(m1, (f32x4*)(mrow + 4));
}

// --------------------------------------------------------------------------
extern "C" void kernel_launch(void* const* d_in, const int* in_sizes, int n_in,
                              void* d_out, int out_size, void* d_ws, size_t ws_size,
                              hipStream_t stream) {
    const int*   x    = (const int*)d_in[0];
    const float* w    = (const float*)d_in[1];
    const float* bias = (const float*)d_in[2];

    float* emb  = (float*)d_out;                                   // [8,2048,1024]
    float* mask = (float*)d_out + (size_t)BATCH * SEQ * D_MODEL;   // [8,2048,2048]

    const size_t pe_bytes = (size_t)SEQ * D_MODEL * sizeof(float); // 8 MB

    dim3 grid(SEQ, BATCH);
    dim3 block(256);

    if (ws_size >= pe_bytes) {
        float* pe = (float*)d_ws;
        pe_kernel<<<dim3(SEQ), block, 0, stream>>>(pe);
        emb_mask_kernel<true><<<grid, block, 0, stream>>>(x, w, bias, pe, emb, mask);
    } else {
        emb_mask_kernel<false><<<grid, block, 0, stream>>>(x, w, bias, nullptr, emb, mask);
    }
}

// Round 2
// 332.003 us; speedup vs baseline: 1.7565x; 1.7565x over previous
//
#include <hip/hip_runtime.h>
#include <math.h>

#define D_MODEL 1024
#define SEQ     2048
#define BATCH   8
#define VOCAB   32000
#define PAD_ID  2

typedef float f32x4 __attribute__((ext_vector_type(4)));

// log2(10000) / 1024
#define INV_EXP_C (13.287712379549449f / 1024.0f)

// --------------------------------------------------------------------------
// PE table: pe[s*D_MODEL + d]
//   d even: cos((s+1) * 10000^(-d/1024))
//   d odd : sin((s+1) * 10000^(-(d+1)/1024))
// --------------------------------------------------------------------------
__global__ __launch_bounds__(256) void pe_kernel(float* __restrict__ pe) {
    const int s  = blockIdx.x;
    const int d0 = threadIdx.x * 4;
    const float pos = (float)(s + 1);

    const float inv0 = exp2f(-(float)(d0)     * INV_EXP_C);
    const float inv1 = exp2f(-(float)(d0 + 2) * INV_EXP_C);
    const float inv2 = exp2f(-(float)(d0 + 4) * INV_EXP_C);

    float s1, c1;
    sincosf(pos * inv1, &s1, &c1);

    f32x4 v;
    v.x = cosf(pos * inv0);   // i even, exp d0
    v.y = s1;                 // i odd,  exp d0+2
    v.z = c1;                 // i even, exp d0+2
    v.w = sinf(pos * inv2);   // i odd,  exp d0+4

    *(f32x4*)(pe + (size_t)s * D_MODEL + d0) = v;
}

// --------------------------------------------------------------------------
// Tiled transpose with bias fold: wT[v][d] = w[d][v] + bias[d]
// grid (VOCAB/64, D_MODEL/64) = (500, 16), 256 threads.
// LDS tile [64][65] -> conflict-free both phases (stride 65 % 32 == 1).
// --------------------------------------------------------------------------
__global__ __launch_bounds__(256) void transpose_bias_kernel(
        const float* __restrict__ w,
        const float* __restrict__ bias,
        float*       __restrict__ wT) {
    __shared__ float tile[64][65];
    const int v0 = blockIdx.x * 64;
    const int d0 = blockIdx.y * 64;

    // read phase: coalesced along v (minor dim of w)
    {
        const int vx = (threadIdx.x & 15) * 4;
        const int dy = threadIdx.x >> 4;          // 0..15
        #pragma unroll
        for (int i = 0; i < 64; i += 16) {
            const int d = d0 + dy + i;
            const f32x4 val = *(const f32x4*)(w + (size_t)d * VOCAB + v0 + vx);
            const float bv = bias[d];
            tile[dy + i][vx + 0] = val.x + bv;
            tile[dy + i][vx + 1] = val.y + bv;
            tile[dy + i][vx + 2] = val.z + bv;
            tile[dy + i][vx + 3] = val.w + bv;
        }
    }
    __syncthreads();
    // write phase: coalesced along d (minor dim of wT)
    {
        const int dx = (threadIdx.x & 15) * 4;
        const int vy = threadIdx.x >> 4;          // 0..15
        #pragma unroll
        for (int i = 0; i < 64; i += 16) {
            f32x4 o;
            o.x = tile[dx + 0][vy + i];
            o.y = tile[dx + 1][vy + i];
            o.z = tile[dx + 2][vy + i];
            o.w = tile[dx + 3][vy + i];
            *(f32x4*)(wT + (size_t)(v0 + vy + i) * D_MODEL + d0 + dx) = o;
        }
    }
}

// --------------------------------------------------------------------------
// Fused embedding + PE + pad-mask.
// MODE 0: read transposed wT (bias pre-folded)  + pe table
// MODE 1: strided gather from w + bias          + pe table      (fallback)
// MODE 2: strided gather from w + bias          + inline trig   (fallback)
// grid = (SEQ, BATCH), 256 threads.
// --------------------------------------------------------------------------
template <int MODE>
__global__ __launch_bounds__(256) void emb_mask_kernel(
        const int*   __restrict__ x,
        const float* __restrict__ w,     // MODE 0: wT [VOCAB][D_MODEL]; else w [D_MODEL][VOCAB]
        const float* __restrict__ bias,
        const float* __restrict__ pe,
        float*       __restrict__ emb,
        float*       __restrict__ mask) {
    const int s = blockIdx.x;
    const int b = blockIdx.y;
    const int t = threadIdx.x;

    const int tok = x[b * SEQ + s];   // uniform per block
    const int d0 = t * 4;

    f32x4 wv;
    if (MODE == 0) {
        wv = *(const f32x4*)(w + (size_t)tok * D_MODEL + d0);   // coalesced 4 KB row
    } else {
        const float* wc = w + tok;
        const f32x4 bv = *(const f32x4*)(bias + d0);
        wv.x = wc[(size_t)(d0 + 0) * VOCAB] + bv.x;
        wv.y = wc[(size_t)(d0 + 1) * VOCAB] + bv.y;
        wv.z = wc[(size_t)(d0 + 2) * VOCAB] + bv.z;
        wv.w = wc[(size_t)(d0 + 3) * VOCAB] + bv.w;
    }

    f32x4 pv;
    if (MODE == 2) {
        const float pos  = (float)(s + 1);
        const float inv0 = exp2f(-(float)(d0)     * INV_EXP_C);
        const float inv1 = exp2f(-(float)(d0 + 2) * INV_EXP_C);
        const float inv2 = exp2f(-(float)(d0 + 4) * INV_EXP_C);
        float s1, c1;
        sincosf(pos * inv1, &s1, &c1);
        pv.x = cosf(pos * inv0);
        pv.y = s1;
        pv.z = c1;
        pv.w = sinf(pos * inv2);
    } else {
        pv = *(const f32x4*)(pe + (size_t)s * D_MODEL + d0);
    }

    f32x4 o;
    o.x = wv.x + pv.x;
    o.y = wv.y + pv.y;
    o.z = wv.z + pv.z;
    o.w = wv.w + pv.w;

    f32x4* eptr = (f32x4*)(emb + ((size_t)(b * SEQ + s)) * D_MODEL + d0);
    __builtin_nontemporal_store(o, eptr);

    // ---- mask: 8 consecutive j per thread ----
    const int j0 = t * 8;
    const int4 xi0 = *(const int4*)(x + b * SEQ + j0);
    const int4 xi1 = *(const int4*)(x + b * SEQ + j0 + 4);

    f32x4 m0, m1;
    m0.x = (xi0.x == PAD_ID) ? 1.0f : 0.0f;
    m0.y = (xi0.y == PAD_ID) ? 1.0f : 0.0f;
    m0.z = (xi0.z == PAD_ID) ? 1.0f : 0.0f;
    m0.w = (xi0.w == PAD_ID) ? 1.0f : 0.0f;
    m1.x = (xi1.x == PAD_ID) ? 1.0f : 0.0f;
    m1.y = (xi1.y == PAD_ID) ? 1.0f : 0.0f;
    m1.z = (xi1.z == PAD_ID) ? 1.0f : 0.0f;
    m1.w = (xi1.w == PAD_ID) ? 1.0f : 0.0f;

    float* mrow = mask + ((size_t)b * SEQ + s) * SEQ + j0;
    __builtin_nontemporal_store(m0, (f32x4*)mrow);
    __builtin_nontemporal_store(m1, (f32x4*)(mrow + 4));
}

// --------------------------------------------------------------------------
extern "C" void kernel_launch(void* const* d_in, const int* in_sizes, int n_in,
                              void* d_out, int out_size, void* d_ws, size_t ws_size,
                              hipStream_t stream) {
    const int*   x    = (const int*)d_in[0];
    const float* w    = (const float*)d_in[1];
    const float* bias = (const float*)d_in[2];

    float* emb  = (float*)d_out;                                   // [8,2048,1024]
    float* mask = (float*)d_out + (size_t)BATCH * SEQ * D_MODEL;   // [8,2048,2048]

    const size_t wt_floats = (size_t)VOCAB * D_MODEL;              // 131 MB
    const size_t pe_floats = (size_t)SEQ * D_MODEL;                // 8 MB
    const size_t need_full = (wt_floats + pe_floats) * sizeof(float);
    const size_t need_pe   = pe_floats * sizeof(float);

    dim3 grid(SEQ, BATCH);
    dim3 block(256);

    if (ws_size >= need_full) {
        float* wT = (float*)d_ws;
        float* pe = (float*)d_ws + wt_floats;
        pe_kernel<<<dim3(SEQ), block, 0, stream>>>(pe);
        transpose_bias_kernel<<<dim3(VOCAB / 64, D_MODEL / 64), block, 0, stream>>>(w, bias, wT);
        emb_mask_kernel<0><<<grid, block, 0, stream>>>(x, wT, bias, pe, emb, mask);
    } else if (ws_size >= need_pe) {
        float* pe = (float*)d_ws;
        pe_kernel<<<dim3(SEQ), block, 0, stream>>>(pe);
        emb_mask_kernel<1><<<grid, block, 0, stream>>>(x, w, bias, pe, emb, mask);
    } else {
        emb_mask_kernel<2><<<grid, block, 0, stream>>>(x, w, bias, nullptr, emb, mask);
    }
}